// Round 8
// baseline (133.849 us; speedup 1.0000x reference)
//
#include <hip/hip_runtime.h>

#define NN 500
#define SLOPEC 0.01f

typedef unsigned short us;
typedef unsigned int u32;
typedef unsigned long long u64;

// ---- scratch between dispatches (fp32, 16B-aligned) ----
__device__ __align__(16) float g_cfw[NN*128];
__device__ __align__(16) float g_Yw[NN*128];
__device__ __align__(16) float g_Zw[NN*128];
__device__ __align__(16) float g_logA[4000];   // exp(-dist) numerators
__device__ __align__(16) float g_logB[4000];
__device__ int   g_inds[4000];
__device__ int   g_inds_tc[4000];
__device__ int   g_isf32;
__device__ __align__(16) float g_bsumA[128];   // per-KNN-block denominator partials
__device__ __align__(16) float g_bsumB[128];   // (125 used per dir; plain stores)

// ---- staged path (fallback + fp32 case): canonical fp32 copies ----
__device__ __align__(16) float g_imf[16000];
__device__ __align__(16) float g_c[1504];
__device__ __align__(16) float g_ct[1504];
__device__ __align__(16) float g_wc1[2048];
__device__ __align__(16) float g_bc1[64];
__device__ __align__(16) float g_wc2[8192];
__device__ __align__(16) float g_bc2[128];
__device__ __align__(16) float g_wps1[32768];
__device__ __align__(16) float g_bps1[256];
__device__ __align__(16) float g_wps2[32768];
__device__ __align__(16) float g_bps2[128];
__device__ __align__(16) float g_wp1[192];
__device__ __align__(16) float g_bp1[64];
__device__ __align__(16) float g_wp2[8192];
__device__ __align__(16) float g_bp2[128];
__device__ __align__(16) float g_wfc1[16384];
__device__ __align__(16) float g_bfc1[64];
__device__ __align__(16) float g_wfc2[10240];
__device__ __align__(16) float g_bfc2[64];
__device__ __align__(16) float g_wfc[8192];
__device__ __align__(16) float g_bfc[64];

__device__ __forceinline__ float b2f(us u){ return __uint_as_float(((u32)u)<<16); }
__device__ __forceinline__ us f2b(float f){
  u32 u = __float_as_uint(f);
  u32 r = u + 0x7fffu + ((u>>16)&1u);
  return (us)(r>>16);
}
__device__ __forceinline__ float lrelu(float x){ return x >= 0.f ? x : SLOPEC*x; }
__device__ __forceinline__ float dot4(const float4 w, const float* h){
  return w.x*h[0] + w.y*h[1] + w.z*h[2] + w.w*h[3];
}
__device__ __forceinline__ int clampi(int v){ return v < 0 ? 0 : (v >= NN ? NN-1 : v); }

// ---- bf16 direct loaders (host-verified 16B base alignment; all vector
// accesses at element index i%4==0 -> 8B-aligned ushort4) ----
__device__ __forceinline__ float ldb(const void* p, int i){
  return b2f(((const us*)p)[i]);
}
__device__ __forceinline__ float dot4b(const void* w, int i, const float* h){
  ushort4 v = *(const ushort4*)((const us*)w + i);
  return b2f(v.x)*h[0] + b2f(v.y)*h[1] + b2f(v.z)*h[2] + b2f(v.w)*h[3];
}

// ================= bf16 direct path (2 dispatches, no staging) =================
// kA: blocks 0..249 = KNN + exp numerators + denominator partial store;
//     blocks 250..749 = per-point conv chains (round-6-proven structure),
//     inputs read directly as bf16 with vectorized loads.
__global__ __launch_bounds__(256) void kAb(
    const void* imf, const void* cc, const void* ct,
    const void* wc1, const void* bc1, const void* wc2, const void* bc2,
    const void* wps1, const void* bps1, const void* wps2, const void* bps2,
    const void* wp1, const void* bp1, const void* wp2, const void* bp2)
{
  __shared__ __align__(16) float sm[1504];
  __shared__ float s_wsum[4];
  const int tid = threadIdx.x;
  const int b = blockIdx.x;
  if (b < 250) {
    // ---------------- KNN + exp numerators ----------------
    const int dir = (b >= 125);            // 0: query=c, ref=ct ; 1: query=ct, ref=c
    const void* refp = dir ? cc : ct;
    const void* qp   = dir ? ct : cc;
    int* outp = dir ? g_inds_tc : g_inds;
    float* logp = dir ? g_logB : g_logA;
    for (int e = tid; e < 1500; e += 256) sm[e] = ldb(refp, e);
    __syncthreads();
    const int lane = tid & 63;
    const int wv = tid >> 6;
    const int q = b*4 + wv;
    const int qi = q - (dir ? 500 : 0);
    float qx = ldb(qp, qi*3+0), qy = ldb(qp, qi*3+1), qz = ldb(qp, qi*3+2);
    // exact numpy op order: sum(q^2) - 2*dot + sum(r^2)
    float sq = __fadd_rn(__fadd_rn(__fmul_rn(qx,qx),__fmul_rn(qy,qy)),__fmul_rn(qz,qz));
    const u64 SENT = 0xFFFFFFFF00000000ull;   // sentinel carries valid idx 0
    u64 a0=SENT,a1=SENT,a2=SENT,a3=SENT,a4=SENT,a5=SENT,a6=SENT,a7=SENT;
    for (int j = lane; j < NN; j += 64){
      float rx = sm[j*3+0], ry = sm[j*3+1], rz = sm[j*3+2];
      float dt = __fadd_rn(__fadd_rn(__fmul_rn(qx,rx),__fmul_rn(qy,ry)),__fmul_rn(qz,rz));
      float sr = __fadd_rn(__fadd_rn(__fmul_rn(rx,rx),__fmul_rn(ry,ry)),__fmul_rn(rz,rz));
      float d2 = __fadd_rn(__fsub_rn(sq, __fmul_rn(2.f,dt)), sr);
      u32 fb = __float_as_uint(d2);
      fb = (fb & 0x80000000u) ? ~fb : (fb | 0x80000000u);   // monotone float->uint
      u64 key = ((u64)fb << 32) | (u32)j;
      if (key < a0){ u64 t=a0; a0=key; key=t; }
      if (key < a1){ u64 t=a1; a1=key; key=t; }
      if (key < a2){ u64 t=a2; a2=key; key=t; }
      if (key < a3){ u64 t=a3; a3=key; key=t; }
      if (key < a4){ u64 t=a4; a4=key; key=t; }
      if (key < a5){ u64 t=a5; a5=key; key=t; }
      if (key < a6){ u64 t=a6; a6=key; key=t; }
      if (key < a7){ u64 t=a7; a7=key; key=t; }
    }
    float wsum = 0.f;
    #pragma unroll
    for (int r8 = 0; r8 < 8; ++r8){
      u64 m = a0;
      #pragma unroll
      for (int off = 32; off; off >>= 1){
        u64 o = __shfl_xor(m, off);
        if (o < m) m = o;
      }
      bool mine = (a0 == m);
      a0 = mine ? a1 : a0;  a1 = mine ? a2 : a1;  a2 = mine ? a3 : a2;
      a3 = mine ? a4 : a3;  a4 = mine ? a5 : a4;  a5 = mine ? a6 : a5;
      a6 = mine ? a7 : a6;  a7 = mine ? SENT : a7;
      if (lane == 0){
        int idx = (int)(m & 0xffffffffu);
        outp[qi*8 + r8] = idx;
        float rx = sm[idx*3+0], ry = sm[idx*3+1], rz = sm[idx*3+2];
        float dx = __fsub_rn(qx,rx), dy = __fsub_rn(qy,ry), dz = __fsub_rn(qz,rz);
        float s2 = __fadd_rn(__fadd_rn(__fmul_rn(dx,dx),__fmul_rn(dy,dy)),__fmul_rn(dz,dz));
        float v = expf(-sqrtf(s2));   // in [4.5e-5,1]: shift-free safe
        logp[qi*8 + r8] = v;
        wsum += v;
      }
    }
    if (lane == 0) s_wsum[wv] = wsum;
    __syncthreads();
    if (tid == 0){
      float bs = (s_wsum[0] + s_wsum[1]) + (s_wsum[2] + s_wsum[3]);
      (dir ? g_bsumB : g_bsumA)[dir ? (b-125) : b] = bs;   // plain store, no atomic
    }
  } else {
    // ---------------- per-point chain, one point ----------------
    const int p = b - 250;
    float* sx  = sm;          // 3   (c column)
    float* sxi = sm + 4;      // 32  (imf column)
    float* h1  = sm + 64;     // 64
    float* cf  = sm + 128;    // 128
    float* h2  = sm + 256;    // 256
    float* hy  = sm + 512;    // 64
    if (tid < 3)  sx[tid] = ldb(cc, p*3 + tid);
    if (tid >= 32 && tid < 64) sxi[tid-32] = ldb(imf, (tid-32)*NN + p);
    __syncthreads();
    // stage1: h1 = lrelu(pconv1 @ x + b)   (threads 0..63)
    if (tid < 64){
      float acc = ldb(bp1, tid);
      acc += ldb(wp1, tid*3+0)*sx[0];
      acc += ldb(wp1, tid*3+1)*sx[1];
      acc += ldb(wp1, tid*3+2)*sx[2];
      h1[tid] = lrelu(acc);
    }
    __syncthreads();
    // stage2 (t0..127): cf = pconv2 @ h1 + b  (dot64, 2 acc)
    // stage5 (t128..191): hy = lrelu(conv1 @ imf + b)  (dot32, 2 acc)
    if (tid < 128){
      int r = tid;
      float aA = ldb(bp2, r), aB = 0.f;
      #pragma unroll 8
      for (int c4=0; c4<16; c4+=2){
        aA += dot4b(wp2, r*64 + c4*4,     h1 + c4*4);
        aB += dot4b(wp2, r*64 + (c4+1)*4, h1 + c4*4 + 4);
      }
      float acc = aA + aB;
      cf[r] = acc;
      g_cfw[(size_t)p*128 + r] = acc;
    } else if (tid < 192){
      int r = tid - 128;
      float aA = ldb(bc1, r), aB = 0.f;
      #pragma unroll 4
      for (int c4=0; c4<8; c4+=2){
        aA += dot4b(wc1, r*32 + c4*4,     sxi + c4*4);
        aB += dot4b(wc1, r*32 + (c4+1)*4, sxi + c4*4 + 4);
      }
      hy[r] = lrelu(aA + aB);
    }
    __syncthreads();
    // stage3 (all 256): h2 = lrelu(psconv1 @ cf + b)  (dot128, 2 acc)
    {
      float aA = ldb(bps1, tid), aB = 0.f;
      #pragma unroll 8
      for (int c4=0; c4<32; c4+=2){
        aA += dot4b(wps1, tid*128 + c4*4,     cf + c4*4);
        aB += dot4b(wps1, tid*128 + (c4+1)*4, cf + c4*4 + 4);
      }
      h2[tid] = lrelu(aA + aB);
    }
    __syncthreads();
    // stage4 (t0..127): Z = psconv2 @ h2 + b  (dot256, 4 acc)
    // stage6 (t128..255): Y = conv2 @ hy + b  (dot64, 2 acc)
    if (tid < 128){
      int r = tid;
      float aA = ldb(bps2, r), aB = 0.f, aC = 0.f, aD = 0.f;
      #pragma unroll 8
      for (int c4=0; c4<64; c4+=4){
        aA += dot4b(wps2, r*256 + c4*4,     h2 + c4*4);
        aB += dot4b(wps2, r*256 + (c4+1)*4, h2 + c4*4 + 4);
        aC += dot4b(wps2, r*256 + (c4+2)*4, h2 + c4*4 + 8);
        aD += dot4b(wps2, r*256 + (c4+3)*4, h2 + c4*4 + 12);
      }
      g_Zw[(size_t)p*128 + r] = (aA + aB) + (aC + aD);
    } else {
      int r = tid - 128;
      float aA = ldb(bc2, r), aB = 0.f;
      #pragma unroll 8
      for (int c4=0; c4<16; c4+=2){
        aA += dot4b(wc2, r*64 + c4*4,     hy + c4*4);
        aB += dot4b(wc2, r*64 + (c4+1)*4, hy + c4*4 + 4);
      }
      g_Yw[(size_t)p*128 + r] = aA + aB;
    }
  }
}

// kBb: ONE point per block (500 blocks): deterministic denominator reduce +
// weighted gather-mean + fc chain -> bf16 out.
__global__ __launch_bounds__(256) void kBb(const void* imf, const void* wfc1,
    const void* bfc1, const void* wfc2, const void* bfc2,
    const void* wfc, const void* bfc, void* outv)
{
  __shared__ __align__(16) float sm[600];
  float* sb1 = sm;          // 256 : [sf | cf]
  float* sb2 = sm + 256;    // 160 : [sfp | imf]
  float* sg  = sm + 416;    // 128 : lrelu([f2 ; f1])
  float* swa = sm + 544;    // 8
  float* swb = sm + 552;    // 8
  int* sia = (int*)(sm + 560);  // 8
  int* sib = (int*)(sm + 568);  // 8
  float* sden = sm + 576;   // 2
  const int tid = threadIdx.x;
  const int p = blockIdx.x;
  // ---- denominators: fixed-order reduce of 125 partials (deterministic) ----
  if (tid < 64){
    float vA = g_bsumA[tid];
    float vB = g_bsumB[tid];
    if (tid + 64 < 125){ vA += g_bsumA[tid+64]; vB += g_bsumB[tid+64]; }
    #pragma unroll
    for (int off = 32; off; off >>= 1){
      vA += __shfl_xor(vA, off);
      vB += __shfl_xor(vB, off);
    }
    if (tid == 0){ sden[0] = vA; sden[1] = vB; }
  }
  // ---- staging (disjoint tid ranges; barrier below covers all) ----
  if (tid >= 224 && tid < 232){
    int t = tid - 224;
    sia[t] = clampi(g_inds[p*8 + t]);
    sib[t] = clampi(g_inds_tc[p*8 + t]);
  }
  if (tid >= 64 && tid < 192) sb1[128 + (tid-64)] = g_cfw[(size_t)p*128 + (tid-64)];
  if (tid >= 192 && tid < 224) sb2[128 + (tid-192)] = ldb(imf, (tid-192)*NN + p);
  __syncthreads();
  if (tid < 8){
    swa[tid] = g_logA[p*8 + tid] / sden[0];
    swb[tid] = g_logB[p*8 + tid] / sden[1];
  }
  __syncthreads();
  // gather-mean: t0..127 -> sf (from Y), t128..255 -> sfp (from Z)
  if (tid < 128){
    int r = tid;
    float acc = 0.f;
    #pragma unroll
    for (int j=0;j<8;++j) acc += swa[j] * g_Yw[(size_t)sia[j]*128 + r];
    sb1[r] = acc * 0.125f;
  } else {
    int r = tid - 128;
    float acc = 0.f;
    #pragma unroll
    for (int j=0;j<8;++j) acc += swb[j] * g_Zw[(size_t)sib[j]*128 + r];
    sb2[r] = acc * 0.125f;
  }
  __syncthreads();
  // f1 (t0..63, dot256, 4 acc) ; f2 (t64..127, dot160, 2 acc); g = lrelu([f2 ; f1])
  if (tid < 64){
    int r = tid;
    float aA = ldb(bfc1, r), aB = 0.f, aC = 0.f, aD = 0.f;
    #pragma unroll 8
    for (int c4=0; c4<64; c4+=4){
      aA += dot4b(wfc1, r*256 + c4*4,     sb1 + c4*4);
      aB += dot4b(wfc1, r*256 + (c4+1)*4, sb1 + c4*4 + 4);
      aC += dot4b(wfc1, r*256 + (c4+2)*4, sb1 + c4*4 + 8);
      aD += dot4b(wfc1, r*256 + (c4+3)*4, sb1 + c4*4 + 12);
    }
    sg[64 + r] = lrelu((aA + aB) + (aC + aD));
  } else if (tid < 128){
    int r = tid - 64;
    float aA = ldb(bfc2, r), aB = 0.f;
    #pragma unroll 8
    for (int c4=0; c4<40; c4+=2){
      aA += dot4b(wfc2, r*160 + c4*4,     sb2 + c4*4);
      aB += dot4b(wfc2, r*160 + (c4+1)*4, sb2 + c4*4 + 4);
    }
    sg[r] = lrelu(aA + aB);
  }
  __syncthreads();
  // out = wfc @ g + b (t0..63, dot128, 2 acc)
  if (tid < 64){
    int r = tid;
    float aA = ldb(bfc, r), aB = 0.f;
    #pragma unroll 8
    for (int c4=0; c4<32; c4+=2){
      aA += dot4b(wfc, r*128 + c4*4,     sg + c4*4);
      aB += dot4b(wfc, r*128 + (c4+1)*4, sg + c4*4 + 4);
    }
    float a = aA + aB;
    ((us*)outv)[r*NN + p] = f2b(a);
  }
}

// ================== staged path (round-6 verbatim; fp32 + fallback) ==================
__global__ __launch_bounds__(256) void k0(
    const void* in0, const void* in1, const void* in2, const void* in3,
    const void* in4, const void* in5, const void* in6, const void* in7,
    const void* in8, const void* in9, const void* in10, const void* in11,
    const void* in12, const void* in13, const void* in14, const void* in15,
    const void* in16, const void* in17, const void* in18, const void* in19,
    const void* in20)
{
  __shared__ int sflag;
  const int tid = threadIdx.x;
  if (tid < 64){
    const us* u = (const us*)in0;
    int cnt = 0;
    #pragma unroll
    for (int j = 0; j < 8; ++j){
      us v = u[2*(tid*8+j)];
      int e = (v >> 7) & 0xff;
      cnt += (e >= 143);
    }
    #pragma unroll
    for (int off = 32; off; off >>= 1) cnt += __shfl_xor(cnt, off);
    if (tid == 0){ sflag = (cnt > 16); g_isf32 = (cnt > 16); }
  }
  __syncthreads();
  const int isf32 = sflag;
  const int g0 = blockIdx.x*256 + tid;
  const int gs = gridDim.x*256;
  #define CVT(src, dst, n) \
    for (int i = g0; i < (n); i += gs) \
      dst[i] = isf32 ? ((const float*)(src))[i] : b2f(((const us*)(src))[i]);
  CVT(in0,  g_imf, 16000)
  CVT(in1,  g_c,   1500)
  CVT(in2,  g_ct,  1500)
  CVT(in3,  g_wc1, 2048)
  CVT(in4,  g_bc1, 64)
  CVT(in5,  g_wc2, 8192)
  CVT(in6,  g_bc2, 128)
  CVT(in7,  g_wps1,32768)
  CVT(in8,  g_bps1,256)
  CVT(in9,  g_wps2,32768)
  CVT(in10, g_bps2,128)
  CVT(in11, g_wp1, 192)
  CVT(in12, g_bp1, 64)
  CVT(in13, g_wp2, 8192)
  CVT(in14, g_bp2, 128)
  CVT(in15, g_wfc1,16384)
  CVT(in16, g_bfc1,64)
  CVT(in17, g_wfc2,10240)
  CVT(in18, g_bfc2,64)
  CVT(in19, g_wfc, 8192)
  CVT(in20, g_bfc, 64)
  #undef CVT
}

__global__ __launch_bounds__(256) void k1()
{
  __shared__ __align__(16) float sm[1504];
  __shared__ float s_wsum[4];
  const int tid = threadIdx.x;
  const int b = blockIdx.x;
  if (b < 250) {
    const int dir = (b >= 125);
    const float* refp = dir ? g_c : g_ct;
    const float* qp   = dir ? g_ct : g_c;
    int* outp = dir ? g_inds_tc : g_inds;
    float* logp = dir ? g_logB : g_logA;
    for (int e = tid; e < 1500; e += 256) sm[e] = refp[e];
    __syncthreads();
    const int lane = tid & 63;
    const int wv = tid >> 6;
    const int q = b*4 + wv;
    const int qi = q - (dir ? 500 : 0);
    float qx = qp[qi*3+0], qy = qp[qi*3+1], qz = qp[qi*3+2];
    float sq = __fadd_rn(__fadd_rn(__fmul_rn(qx,qx),__fmul_rn(qy,qy)),__fmul_rn(qz,qz));
    const u64 SENT = 0xFFFFFFFF00000000ull;
    u64 a0=SENT,a1=SENT,a2=SENT,a3=SENT,a4=SENT,a5=SENT,a6=SENT,a7=SENT;
    for (int j = lane; j < NN; j += 64){
      float rx = sm[j*3+0], ry = sm[j*3+1], rz = sm[j*3+2];
      float dt = __fadd_rn(__fadd_rn(__fmul_rn(qx,rx),__fmul_rn(qy,ry)),__fmul_rn(qz,rz));
      float sr = __fadd_rn(__fadd_rn(__fmul_rn(rx,rx),__fmul_rn(ry,ry)),__fmul_rn(rz,rz));
      float d2 = __fadd_rn(__fsub_rn(sq, __fmul_rn(2.f,dt)), sr);
      u32 fb = __float_as_uint(d2);
      fb = (fb & 0x80000000u) ? ~fb : (fb | 0x80000000u);
      u64 key = ((u64)fb << 32) | (u32)j;
      if (key < a0){ u64 t=a0; a0=key; key=t; }
      if (key < a1){ u64 t=a1; a1=key; key=t; }
      if (key < a2){ u64 t=a2; a2=key; key=t; }
      if (key < a3){ u64 t=a3; a3=key; key=t; }
      if (key < a4){ u64 t=a4; a4=key; key=t; }
      if (key < a5){ u64 t=a5; a5=key; key=t; }
      if (key < a6){ u64 t=a6; a6=key; key=t; }
      if (key < a7){ u64 t=a7; a7=key; key=t; }
    }
    float wsum = 0.f;
    #pragma unroll
    for (int r8 = 0; r8 < 8; ++r8){
      u64 m = a0;
      #pragma unroll
      for (int off = 32; off; off >>= 1){
        u64 o = __shfl_xor(m, off);
        if (o < m) m = o;
      }
      bool mine = (a0 == m);
      a0 = mine ? a1 : a0;  a1 = mine ? a2 : a1;  a2 = mine ? a3 : a2;
      a3 = mine ? a4 : a3;  a4 = mine ? a5 : a4;  a5 = mine ? a6 : a5;
      a6 = mine ? a7 : a6;  a7 = mine ? SENT : a7;
      if (lane == 0){
        int idx = (int)(m & 0xffffffffu);
        outp[qi*8 + r8] = idx;
        float rx = sm[idx*3+0], ry = sm[idx*3+1], rz = sm[idx*3+2];
        float dx = __fsub_rn(qx,rx), dy = __fsub_rn(qy,ry), dz = __fsub_rn(qz,rz);
        float s2 = __fadd_rn(__fadd_rn(__fmul_rn(dx,dx),__fmul_rn(dy,dy)),__fmul_rn(dz,dz));
        float v = expf(-sqrtf(s2));
        logp[qi*8 + r8] = v;
        wsum += v;
      }
    }
    if (lane == 0) s_wsum[wv] = wsum;
    __syncthreads();
    if (tid == 0){
      float bs = (s_wsum[0] + s_wsum[1]) + (s_wsum[2] + s_wsum[3]);
      (dir ? g_bsumB : g_bsumA)[dir ? (b-125) : b] = bs;
    }
  } else {
    const int p = b - 250;
    float* sx  = sm;
    float* sxi = sm + 4;
    float* h1  = sm + 64;
    float* cf  = sm + 128;
    float* h2  = sm + 256;
    float* hy  = sm + 512;
    if (tid < 3)  sx[tid] = g_c[p*3 + tid];
    if (tid >= 32 && tid < 64) sxi[tid-32] = g_imf[(tid-32)*NN + p];
    __syncthreads();
    if (tid < 64){
      float acc = g_bp1[tid];
      acc += g_wp1[tid*3+0]*sx[0];
      acc += g_wp1[tid*3+1]*sx[1];
      acc += g_wp1[tid*3+2]*sx[2];
      h1[tid] = lrelu(acc);
    }
    __syncthreads();
    if (tid < 128){
      int r = tid;
      float aA = g_bp2[r], aB = 0.f;
      const float4* wrow = (const float4*)(g_wp2 + (size_t)r*64);
      #pragma unroll 8
      for (int c4=0; c4<16; c4+=2){
        aA += dot4(wrow[c4],   h1 + c4*4);
        aB += dot4(wrow[c4+1], h1 + c4*4 + 4);
      }
      float acc = aA + aB;
      cf[r] = acc;
      g_cfw[(size_t)p*128 + r] = acc;
    } else if (tid < 192){
      int r = tid - 128;
      float aA = g_bc1[r], aB = 0.f;
      const float4* wrow = (const float4*)(g_wc1 + (size_t)r*32);
      #pragma unroll 4
      for (int c4=0; c4<8; c4+=2){
        aA += dot4(wrow[c4],   sxi + c4*4);
        aB += dot4(wrow[c4+1], sxi + c4*4 + 4);
      }
      hy[r] = lrelu(aA + aB);
    }
    __syncthreads();
    {
      float aA = g_bps1[tid], aB = 0.f;
      const float4* wrow = (const float4*)(g_wps1 + (size_t)tid*128);
      #pragma unroll 8
      for (int c4=0; c4<32; c4+=2){
        aA += dot4(wrow[c4],   cf + c4*4);
        aB += dot4(wrow[c4+1], cf + c4*4 + 4);
      }
      h2[tid] = lrelu(aA + aB);
    }
    __syncthreads();
    if (tid < 128){
      int r = tid;
      float aA = g_bps2[r], aB = 0.f, aC = 0.f, aD = 0.f;
      const float4* wrow = (const float4*)(g_wps2 + (size_t)r*256);
      #pragma unroll 8
      for (int c4=0; c4<64; c4+=4){
        aA += dot4(wrow[c4],   h2 + c4*4);
        aB += dot4(wrow[c4+1], h2 + c4*4 + 4);
        aC += dot4(wrow[c4+2], h2 + c4*4 + 8);
        aD += dot4(wrow[c4+3], h2 + c4*4 + 12);
      }
      g_Zw[(size_t)p*128 + r] = (aA + aB) + (aC + aD);
    } else {
      int r = tid - 128;
      float aA = g_bc2[r], aB = 0.f;
      const float4* wrow = (const float4*)(g_wc2 + (size_t)r*64);
      #pragma unroll 8
      for (int c4=0; c4<16; c4+=2){
        aA += dot4(wrow[c4],   hy + c4*4);
        aB += dot4(wrow[c4+1], hy + c4*4 + 4);
      }
      g_Yw[(size_t)p*128 + r] = aA + aB;
    }
  }
}

__global__ __launch_bounds__(256) void k3(void* outv)
{
  __shared__ __align__(16) float sm[600];
  float* sb1 = sm;
  float* sb2 = sm + 256;
  float* sg  = sm + 416;
  float* swa = sm + 544;
  float* swb = sm + 552;
  int* sia = (int*)(sm + 560);
  int* sib = (int*)(sm + 568);
  float* sden = sm + 576;
  const int tid = threadIdx.x;
  const int p = blockIdx.x;
  const int of32 = g_isf32;
  if (tid < 64){
    float vA = g_bsumA[tid];
    float vB = g_bsumB[tid];
    if (tid + 64 < 125){ vA += g_bsumA[tid+64]; vB += g_bsumB[tid+64]; }
    #pragma unroll
    for (int off = 32; off; off >>= 1){
      vA += __shfl_xor(vA, off);
      vB += __shfl_xor(vB, off);
    }
    if (tid == 0){ sden[0] = vA; sden[1] = vB; }
  }
  if (tid >= 224 && tid < 232){
    int t = tid - 224;
    sia[t] = clampi(g_inds[p*8 + t]);
    sib[t] = clampi(g_inds_tc[p*8 + t]);
  }
  if (tid >= 64 && tid < 192) sb1[128 + (tid-64)] = g_cfw[(size_t)p*128 + (tid-64)];
  if (tid >= 192 && tid < 224) sb2[128 + (tid-192)] = g_imf[(tid-192)*NN + p];
  __syncthreads();
  if (tid < 8){
    swa[tid] = g_logA[p*8 + tid] / sden[0];
    swb[tid] = g_logB[p*8 + tid] / sden[1];
  }
  __syncthreads();
  if (tid < 128){
    int r = tid;
    float acc = 0.f;
    #pragma unroll
    for (int j=0;j<8;++j) acc += swa[j] * g_Yw[(size_t)sia[j]*128 + r];
    sb1[r] = acc * 0.125f;
  } else {
    int r = tid - 128;
    float acc = 0.f;
    #pragma unroll
    for (int j=0;j<8;++j) acc += swb[j] * g_Zw[(size_t)sib[j]*128 + r];
    sb2[r] = acc * 0.125f;
  }
  __syncthreads();
  if (tid < 64){
    int r = tid;
    float aA = g_bfc1[r], aB = 0.f, aC = 0.f, aD = 0.f;
    const float4* w1 = (const float4*)(g_wfc1 + (size_t)r*256);
    #pragma unroll 8
    for (int c4=0; c4<64; c4+=4){
      aA += dot4(w1[c4],   sb1 + c4*4);
      aB += dot4(w1[c4+1], sb1 + c4*4 + 4);
      aC += dot4(w1[c4+2], sb1 + c4*4 + 8);
      aD += dot4(w1[c4+3], sb1 + c4*4 + 12);
    }
    sg[64 + r] = lrelu((aA + aB) + (aC + aD));
  } else if (tid < 128){
    int r = tid - 64;
    float aA = g_bfc2[r], aB = 0.f;
    const float4* w2 = (const float4*)(g_wfc2 + (size_t)r*160);
    #pragma unroll 8
    for (int c4=0; c4<40; c4+=2){
      aA += dot4(w2[c4],   sb2 + c4*4);
      aB += dot4(w2[c4+1], sb2 + c4*4 + 4);
    }
    sg[r] = lrelu(aA + aB);
  }
  __syncthreads();
  if (tid < 64){
    int r = tid;
    float aA = g_bfc[r], aB = 0.f;
    const float4* w3 = (const float4*)(g_wfc + (size_t)r*128);
    #pragma unroll 8
    for (int c4=0; c4<32; c4+=2){
      aA += dot4(w3[c4],   sg + c4*4);
      aB += dot4(w3[c4+1], sg + c4*4 + 4);
    }
    float a = aA + aB;
    if (of32) ((float*)outv)[r*NN + p] = a;
    else      ((us*)outv)[r*NN + p] = f2b(a);
  }
}

extern "C" void kernel_launch(void* const* d_in, const int* in_sizes, int n_in,
                              void* d_out, int out_size, void* d_ws, size_t ws_size,
                              hipStream_t stream)
{
  (void)d_ws; (void)ws_size; (void)out_size;
  // Host-side specialization: bf16 iff img_feat buffer is 32000 B (16000 elems).
  // Direct path additionally requires 16B-aligned pointers (prior session saw
  // NaNs from vectorized loads on harness buffers -> alignment gate).
  bool bf16 = (n_in > 0) && (in_sizes[0] == 32000);
  bool aligned = ((((size_t)d_out) & 15) == 0);
  for (int i = 0; i < n_in && i < 21; ++i)
    aligned = aligned && ((((size_t)d_in[i]) & 15) == 0);

  if (bf16 && aligned){
    kAb<<<750, 256, 0, stream>>>(
      d_in[0], d_in[1], d_in[2], d_in[3], d_in[4], d_in[5], d_in[6],
      d_in[7], d_in[8], d_in[9], d_in[10], d_in[11], d_in[12], d_in[13], d_in[14]);
    kBb<<<500, 256, 0, stream>>>(
      d_in[0], d_in[15], d_in[16], d_in[17], d_in[18], d_in[19], d_in[20], d_out);
  } else {
    // proven round-6 staged path (device-side dtype detect)
    k0<<<256, 256, 0, stream>>>(
      d_in[0], d_in[1], d_in[2], d_in[3], d_in[4], d_in[5], d_in[6],
      d_in[7], d_in[8], d_in[9], d_in[10], d_in[11], d_in[12], d_in[13],
      d_in[14], d_in[15], d_in[16], d_in[17], d_in[18], d_in[19], d_in[20]);
    k1<<<750, 256, 0, stream>>>();
    k3<<<500, 256, 0, stream>>>(d_out);
  }
}